// Round 6
// baseline (1678.240 us; speedup 1.0000x reference)
//
#include <hip/hip_runtime.h>

// ScaledDotProductAttention: B=4 H=16 S=2048 DK=128, fp32 in, int32 mask.
// Outputs (concatenated in d_out): out (B,H,S,DK) fp32 then weights (B,H,S,S) fp32.
//
// R5: break the LDS-occupancy jail (R2-R4 latency-bound at 2 blocks/CU, lockstep waves).
//  - NO 64KB P buffer: pass A computes exp(QK^T) only for ROW SUMS (mask bits stashed
//    in 4 VGPRs); pass B recomputes S, normalizes, writes weights, and does PV via a
//    tiny per-wave 16x32 LDS bounce tile (no barriers in main loops).
//  - 256-thread blocks, 4 waves k-striped (512 cols each), LDS ~39KB -> 4 blocks/CU,
//    blocks desynchronize -> latency hiding across phases.
//  - final cross-wave out reduce via padded 32KB LDS + one barrier.
//  - prepass: K fp32->fp16 [bh][k][d]; V fp32->fp16 transposed [bh][d][k] (in ws).

constexpr int Sc = 2048, Dc = 128;
constexpr int BHc = 64;
constexpr int QB = 16;
constexpr int NQT = Sc / QB;       // 128
constexpr int NBLK = BHc * NQT;    // 8192
constexpr long OUTE = (long)BHc * Sc * Dc;   // out elements (start of weights region)
constexpr long KVE  = (long)BHc * Sc * Dc;   // elements per K/V plane
#define SCALEF 0.088388347648318447f         // 1/sqrt(128)

typedef __attribute__((ext_vector_type(4))) float f32x4;
typedef _Float16 f16x8 __attribute__((ext_vector_type(8)));

static __device__ __forceinline__ f16x8 loadcvt8h(const float* __restrict__ p) {
  float4 a = *(const float4*)p;
  float4 b = *(const float4*)(p + 4);
  f16x8 r;
  r[0] = (_Float16)a.x; r[1] = (_Float16)a.y; r[2] = (_Float16)a.z; r[3] = (_Float16)a.w;
  r[4] = (_Float16)b.x; r[5] = (_Float16)b.y; r[6] = (_Float16)b.z; r[7] = (_Float16)b.w;
  return r;
}

// ---- prepass A: K fp32 -> fp16, same [bh][k][d] layout. 8 elems/thread.
__global__ __launch_bounds__(256)
void kconv_kernel(const float* __restrict__ K, _Float16* __restrict__ Kh) {
  long i = ((long)blockIdx.x * 256 + threadIdx.x) * 8;
  f16x8 v = loadcvt8h(K + i);
  *(f16x8*)(Kh + i) = v;
}

// ---- prepass B: V fp32 [bh][k][d] -> fp16 transposed [bh][d][k].
__global__ __launch_bounds__(256)
void vtrans_kernel(const float* __restrict__ V, _Float16* __restrict__ Vt) {
  __shared__ _Float16 sT[Dc][64 + 2];
  const int bh = blockIdx.x >> 5;
  const int kt = blockIdx.x & 31;
  const int tid = threadIdx.x;
  const float* vb = V + ((long)bh * Sc + kt * 64) * Dc;
  #pragma unroll
  for (int i = 0; i < 8; i++) {
    int e = tid + i * 256;
    int ki = e >> 5;
    int dq = (e & 31) * 4;
    float4 f = *(const float4*)(vb + (long)ki * Dc + dq);
    sT[dq + 0][ki] = (_Float16)f.x;
    sT[dq + 1][ki] = (_Float16)f.y;
    sT[dq + 2][ki] = (_Float16)f.z;
    sT[dq + 3][ki] = (_Float16)f.w;
  }
  __syncthreads();
  #pragma unroll
  for (int i = 0; i < 4; i++) {
    int chunk = tid + i * 256;
    int d = chunk >> 3;
    int kc = (chunk & 7) * 8;
    f16x8 o;
    #pragma unroll
    for (int j = 0; j < 8; j++) o[j] = sT[d][kc + j];
    *(f16x8*)(Vt + ((long)bh * Dc + d) * Sc + kt * 64 + kc) = o;
  }
}

template <bool PRE>
__global__ __launch_bounds__(256, 4)
void sdpa_kernel(const float* __restrict__ Qg, const float* __restrict__ Kg,
                 const float* __restrict__ Vg, const int* __restrict__ Mg,
                 float* __restrict__ Og, const _Float16* __restrict__ Kh,
                 const _Float16* __restrict__ Vt) {
  __shared__ __align__(16) _Float16 sPt[4][QB][40];     // per-wave P bounce, padded (5 KB)
  __shared__ __align__(16) float sOred[4][QB][132];     // out reduce, padded (~33 KB)
  __shared__ float sRsum[4][QB];
  __shared__ float sRinv[QB];

  const int bid0 = blockIdx.x;
  const int bid  = (bid0 & 7) * (NBLK >> 3) + (bid0 >> 3);   // XCD-chunked swizzle
  const int bh = bid >> 7;
  const int qt = bid & (NQT - 1);

  const int tid  = threadIdx.x;
  const int lane = tid & 63;
  const int wave = tid >> 6;        // 0..3; wave owns k-cols [wave*512, wave*512+512)
  const int g = lane >> 4;          // 0..3 (k-group of MFMA operand)
  const int c = lane & 15;          // 0..15 (A row / B col / D col)

  // ---- Q A-fragments: lane holds Q[qrow=c][d = ch*32 + g*8 + j]
  f16x8 aq[4];
  {
    const float* qp = Qg + ((long)bh * Sc + (long)qt * QB + c) * Dc + g * 8;
    #pragma unroll
    for (int ch = 0; ch < 4; ch++) aq[ch] = loadcvt8h(qp + ch * 32);
  }

  const long mbase = ((long)bh * Sc + (long)qt * QB) * Sc;
  const int ktb = wave * 32;        // first 16-col k-tile of this wave's stripe

  auto loadK = [&](f16x8* dst, int t) {
    if constexpr (PRE) {
      const _Float16* kp = Kh + ((long)bh * Sc + (long)((ktb + t) * 16 + c)) * Dc + g * 8;
      dst[0] = *(const f16x8*)kp;
      dst[1] = *(const f16x8*)(kp + 32);
      dst[2] = *(const f16x8*)(kp + 64);
      dst[3] = *(const f16x8*)(kp + 96);
    } else {
      const float* kp = Kg + ((long)bh * Sc + (long)((ktb + t) * 16 + c)) * Dc + g * 8;
      dst[0] = loadcvt8h(kp);      dst[1] = loadcvt8h(kp + 32);
      dst[2] = loadcvt8h(kp + 64); dst[3] = loadcvt8h(kp + 96);
    }
  };
  auto loadM = [&](int* dst, int t) {
    const int* mp = Mg + mbase + (long)((ktb + t) * 16 + c);
    #pragma unroll
    for (int r = 0; r < 4; r++) dst[r] = mp[(long)(g * 4 + r) * Sc];
  };

  float rs[4] = {0.f, 0.f, 0.f, 0.f};
  unsigned mst[4];   // mask bit stash: 32 tiles x 4 rows = 128 bits/lane

  // ---- pass A: rowsums of exp(masked S). Ping-pong K+mask prefetch, no barriers.
  {
    f16x8 Kc[4], Kn[4];
    int Mc[4], Mn[4];
    loadK(Kc, 0); loadM(Mc, 0);
    auto bodyA = [&](const f16x8* K, const int* M, int sh, unsigned& mb) {
      f32x4 acc = {0.f, 0.f, 0.f, 0.f};
      acc = __builtin_amdgcn_mfma_f32_16x16x32_f16(aq[0], K[0], acc, 0, 0, 0);
      acc = __builtin_amdgcn_mfma_f32_16x16x32_f16(aq[1], K[1], acc, 0, 0, 0);
      acc = __builtin_amdgcn_mfma_f32_16x16x32_f16(aq[2], K[2], acc, 0, 0, 0);
      acc = __builtin_amdgcn_mfma_f32_16x16x32_f16(aq[3], K[3], acc, 0, 0, 0);
      #pragma unroll
      for (int r = 0; r < 4; r++) {
        float e = (M[r] != 0) ? __expf(acc[r] * SCALEF) : 0.0f;
        _Float16 eh = (_Float16)e;
        rs[r] += (float)eh;   // fp16-rounded so weights sum ~exactly to 1
        mb |= (M[r] != 0 ? 1u : 0u) << (sh | r);
      }
    };
    #pragma unroll
    for (int mr = 0; mr < 4; mr++) {    // compile-time mr -> static mst index
      unsigned mb = 0;
      #pragma unroll 1
      for (int tt = 0; tt < 8; tt += 2) {
        const int t = mr * 8 + tt;
        loadK(Kn, t + 1); loadM(Mn, t + 1);
        bodyA(Kc, Mc, (tt << 2), mb);
        if (t + 2 < 32) { loadK(Kc, t + 2); loadM(Mc, t + 2); }
        bodyA(Kn, Mn, ((tt + 1) << 2), mb);
      }
      mst[mr] = mb;
    }
  }

  // cross-lane + cross-wave rowsum -> sRinv
  #pragma unroll
  for (int r = 0; r < 4; r++) {
    float x = rs[r];
    x += __shfl_xor(x, 1);
    x += __shfl_xor(x, 2);
    x += __shfl_xor(x, 4);
    x += __shfl_xor(x, 8);
    rs[r] = x;
  }
  if (c == 0) {
    #pragma unroll
    for (int r = 0; r < 4; r++) sRsum[wave][g * 4 + r] = rs[r];
  }
  __syncthreads();
  if (tid < QB) {
    float t = sRsum[0][tid] + sRsum[1][tid] + sRsum[2][tid] + sRsum[3][tid];
    sRinv[tid] = (t > 0.0f) ? (1.0f / t) : 0.0f;
  }
  __syncthreads();

  // ---- pass B: recompute S -> P tile pair (fp16) -> bounce -> weights write + PV.
  const float riW = sRinv[lane >> 2];   // weights-write row = lane>>2
  const int wrow = lane >> 2;
  const int wcb = (lane & 3) * 8;
  float* wb = Og + OUTE + ((long)bh * Sc + (long)qt * QB) * Sc;

  f32x4 oacc[8];
  #pragma unroll
  for (int n = 0; n < 8; n++) oacc[n] = (f32x4){0.f, 0.f, 0.f, 0.f};

  auto loadVt = [&](int n, int p) -> f16x8 {
    if constexpr (PRE) {
      return *(const f16x8*)(Vt + ((long)bh * Dc + n * 16 + c) * Sc +
                             (long)(ktb * 16 + p * 32 + g * 8));
    } else {
      const float* vp = Vg + ((long)bh * Sc + ktb * 16 + p * 32 + g * 8) * Dc + n * 16 + c;
      f16x8 r;
      #pragma unroll
      for (int j = 0; j < 8; j++) r[j] = (_Float16)vp[(long)j * Dc];
      return r;
    }
  };

  #pragma unroll
  for (int mr = 0; mr < 4; mr++) {      // compile-time mr -> static mst index
    const unsigned mb = mst[mr];
    #pragma unroll 1
    for (int pp = 0; pp < 4; pp++) {
      const int p = mr * 4 + pp;        // pair index 0..15; covers tiles 2p, 2p+1
      const int shA = ((2 * pp) << 2);  // bit base within mb for tile 2p (tt = 2p - 8mr)
      const int shB = ((2 * pp + 1) << 2);
      // Vt batch 1 (independent of everything -> issues early, hides under S work)
      f16x8 bv0 = loadVt(0, p), bv1 = loadVt(1, p), bv2 = loadVt(2, p), bv3 = loadVt(3, p);
      // K pair + S recompute (bit-identical to pass A)
      f16x8 KA[4], KB[4];
      loadK(KA, 2 * p); loadK(KB, 2 * p + 1);
      f32x4 sA = {0.f, 0.f, 0.f, 0.f}, sB = {0.f, 0.f, 0.f, 0.f};
      sA = __builtin_amdgcn_mfma_f32_16x16x32_f16(aq[0], KA[0], sA, 0, 0, 0);
      sA = __builtin_amdgcn_mfma_f32_16x16x32_f16(aq[1], KA[1], sA, 0, 0, 0);
      sA = __builtin_amdgcn_mfma_f32_16x16x32_f16(aq[2], KA[2], sA, 0, 0, 0);
      sA = __builtin_amdgcn_mfma_f32_16x16x32_f16(aq[3], KA[3], sA, 0, 0, 0);
      sB = __builtin_amdgcn_mfma_f32_16x16x32_f16(aq[0], KB[0], sB, 0, 0, 0);
      sB = __builtin_amdgcn_mfma_f32_16x16x32_f16(aq[1], KB[1], sB, 0, 0, 0);
      sB = __builtin_amdgcn_mfma_f32_16x16x32_f16(aq[2], KB[2], sB, 0, 0, 0);
      sB = __builtin_amdgcn_mfma_f32_16x16x32_f16(aq[3], KB[3], sB, 0, 0, 0);
      // exp + bounce to per-wave LDS tile [16][32] (padded to 40)
      #pragma unroll
      for (int r = 0; r < 4; r++) {
        const int row = g * 4 + r;
        float eA = ((mb >> (shA | r)) & 1u) ? __expf(sA[r] * SCALEF) : 0.0f;
        float eB = ((mb >> (shB | r)) & 1u) ? __expf(sB[r] * SCALEF) : 0.0f;
        sPt[wave][row][c]      = (_Float16)eA;
        sPt[wave][row][16 + c] = (_Float16)eB;
      }
      // Vt batch 2
      f16x8 bv4 = loadVt(4, p), bv5 = loadVt(5, p), bv6 = loadVt(6, p), bv7 = loadVt(7, p);
      // A-frag (P) from bounce; weights row-chunk write from bounce (wave-coherent LDS)
      f16x8 af = *(const f16x8*)&sPt[wave][c][g * 8];
      {
        f16x8 pw = *(const f16x8*)&sPt[wave][wrow][wcb];
        float4 w0, w1;
        w0.x = (float)pw[0] * riW; w0.y = (float)pw[1] * riW;
        w0.z = (float)pw[2] * riW; w0.w = (float)pw[3] * riW;
        w1.x = (float)pw[4] * riW; w1.y = (float)pw[5] * riW;
        w1.z = (float)pw[6] * riW; w1.w = (float)pw[7] * riW;
        float* dst = wb + (long)wrow * Sc + ktb * 16 + p * 32 + wcb;
        *(float4*)dst = w0;
        *(float4*)(dst + 4) = w1;
      }
      // PV: 8 independent MFMAs
      oacc[0] = __builtin_amdgcn_mfma_f32_16x16x32_f16(af, bv0, oacc[0], 0, 0, 0);
      oacc[1] = __builtin_amdgcn_mfma_f32_16x16x32_f16(af, bv1, oacc[1], 0, 0, 0);
      oacc[2] = __builtin_amdgcn_mfma_f32_16x16x32_f16(af, bv2, oacc[2], 0, 0, 0);
      oacc[3] = __builtin_amdgcn_mfma_f32_16x16x32_f16(af, bv3, oacc[3], 0, 0, 0);
      oacc[4] = __builtin_amdgcn_mfma_f32_16x16x32_f16(af, bv4, oacc[4], 0, 0, 0);
      oacc[5] = __builtin_amdgcn_mfma_f32_16x16x32_f16(af, bv5, oacc[5], 0, 0, 0);
      oacc[6] = __builtin_amdgcn_mfma_f32_16x16x32_f16(af, bv6, oacc[6], 0, 0, 0);
      oacc[7] = __builtin_amdgcn_mfma_f32_16x16x32_f16(af, bv7, oacc[7], 0, 0, 0);
    }
  }

  // ---- epilogue: cross-wave reduce of out partials, one barrier.
  #pragma unroll
  for (int n = 0; n < 8; n++) {
    #pragma unroll
    for (int r = 0; r < 4; r++) sOred[wave][g * 4 + r][n * 16 + c] = oacc[n][r];
  }
  __syncthreads();
  {
    const int erow = tid >> 4;          // 0..15
    const int ed = (tid & 15) * 8;      // 0..120
    float s0 = 0.f, s1 = 0.f, s2 = 0.f, s3 = 0.f, s4 = 0.f, s5 = 0.f, s6 = 0.f, s7 = 0.f;
    #pragma unroll
    for (int w = 0; w < 4; w++) {
      float4 a = *(const float4*)&sOred[w][erow][ed];
      float4 b = *(const float4*)&sOred[w][erow][ed + 4];
      s0 += a.x; s1 += a.y; s2 += a.z; s3 += a.w;
      s4 += b.x; s5 += b.y; s6 += b.z; s7 += b.w;
    }
    const float ri = sRinv[erow];
    float* ob = Og + ((long)bh * Sc + (long)qt * QB + erow) * Dc + ed;
    float4 o0, o1;
    o0.x = s0 * ri; o0.y = s1 * ri; o0.z = s2 * ri; o0.w = s3 * ri;
    o1.x = s4 * ri; o1.y = s5 * ri; o1.z = s6 * ri; o1.w = s7 * ri;
    *(float4*)ob = o0;
    *(float4*)(ob + 4) = o1;
  }
}

extern "C" void kernel_launch(void* const* d_in, const int* in_sizes, int n_in,
                              void* d_out, int out_size, void* d_ws, size_t ws_size,
                              hipStream_t stream) {
  (void)in_sizes; (void)n_in; (void)out_size;
  const float* q = (const float*)d_in[0];
  const float* k = (const float*)d_in[1];
  const float* v = (const float*)d_in[2];
  const int* m = (const int*)d_in[3];
  float* out = (float*)d_out;

  const size_t need = 2UL * KVE * sizeof(_Float16);  // K fp16 + Vt fp16 = 67 MB
  if (d_ws != nullptr && ws_size >= need) {
    _Float16* Kh = (_Float16*)d_ws;
    _Float16* Vt = Kh + KVE;
    hipLaunchKernelGGL(kconv_kernel, dim3((int)(KVE / 8 / 256)), dim3(256), 0, stream, k, Kh);
    hipLaunchKernelGGL(vtrans_kernel, dim3(BHc * 32), dim3(256), 0, stream, v, Vt);
    hipLaunchKernelGGL((sdpa_kernel<true>), dim3(NBLK), dim3(256), 0, stream,
                       q, k, v, m, out, Kh, Vt);
  } else {
    hipLaunchKernelGGL((sdpa_kernel<false>), dim3(NBLK), dim3(256), 0, stream,
                       q, k, v, m, out, nullptr, nullptr);
  }
}

// Round 9
// 794.869 us; speedup vs baseline: 2.1113x; 2.1113x over previous
//
#include <hip/hip_runtime.h>

// ScaledDotProductAttention: B=4 H=16 S=2048 DK=128, fp32 in, int32 mask.
// Outputs (concatenated in d_out): out (B,H,S,DK) fp32 then weights (B,H,S,S) fp32.
//
// R8: R6/R7 architecture (QBR=128 block, 8 waves, LDS-staged K/V chunks, 2-pass
// recompute) rebuilt from known-good R2-R5 components after two correctness
// failures: direct mask reads (no bitmask prepass), padded-linear LDS (no XOR
// swizzle), reg-staged ds_write, barrier-protected sRinv handoff.

constexpr int Sc = 2048, Dc = 128;
constexpr int BHc = 64;
constexpr long OUTE = (long)BHc * Sc * Dc;   // out elems (start of weights region)
constexpr long KVE  = (long)BHc * Sc * Dc;   // elems per K/V plane
constexpr int QBR = 128;                      // q rows per main block
constexpr int NQT = Sc / QBR;                 // 16
constexpr int NBLK = BHc * NQT;               // 1024
#define SCALEF 0.088388347648318447f          // 1/sqrt(128)

typedef __attribute__((ext_vector_type(4))) float f32x4;
typedef _Float16 f16x8 __attribute__((ext_vector_type(8)));

static __device__ __forceinline__ f16x8 loadcvt8h(const float* __restrict__ p) {
  float4 a = *(const float4*)p;
  float4 b = *(const float4*)(p + 4);
  f16x8 r;
  r[0] = (_Float16)a.x; r[1] = (_Float16)a.y; r[2] = (_Float16)a.z; r[3] = (_Float16)a.w;
  r[4] = (_Float16)b.x; r[5] = (_Float16)b.y; r[6] = (_Float16)b.z; r[7] = (_Float16)b.w;
  return r;
}

// ---- prepass 1: K fp32 -> fp16, [bh][k][d]. 8 elems/thread. (known-good R2-R5)
__global__ __launch_bounds__(256)
void kconv_kernel(const float* __restrict__ K, _Float16* __restrict__ Kh) {
  long i = ((long)blockIdx.x * 256 + threadIdx.x) * 8;
  f16x8 v = loadcvt8h(K + i);
  *(f16x8*)(Kh + i) = v;
}

// ---- prepass 2: V fp32 [bh][k][d] -> fp16 transposed [bh][d][k]. (known-good R2-R5)
__global__ __launch_bounds__(256)
void vtrans_kernel(const float* __restrict__ V, _Float16* __restrict__ Vt) {
  __shared__ _Float16 sT[Dc][64 + 2];
  const int bh = blockIdx.x >> 5;
  const int kt = blockIdx.x & 31;
  const int tid = threadIdx.x;
  const float* vb = V + ((long)bh * Sc + kt * 64) * Dc;
  #pragma unroll
  for (int i = 0; i < 8; i++) {
    int e = tid + i * 256;
    int ki = e >> 5;
    int dq = (e & 31) * 4;
    float4 f = *(const float4*)(vb + (long)ki * Dc + dq);
    sT[dq + 0][ki] = (_Float16)f.x;
    sT[dq + 1][ki] = (_Float16)f.y;
    sT[dq + 2][ki] = (_Float16)f.z;
    sT[dq + 3][ki] = (_Float16)f.w;
  }
  __syncthreads();
  #pragma unroll
  for (int i = 0; i < 4; i++) {
    int chunk = tid + i * 256;
    int d = chunk >> 3;
    int kc = (chunk & 7) * 8;
    f16x8 o;
    #pragma unroll
    for (int j = 0; j < 8; j++) o[j] = sT[d][kc + j];
    *(f16x8*)(Vt + ((long)bh * Dc + d) * Sc + kt * 64 + kc) = o;
  }
}

// ---- main kernel: 1024 blocks x 512 threads, QBR=128 rows, k-chunks of 64 via LDS.
__global__ __launch_bounds__(512, 4)
void sdpa_main(const float* __restrict__ Qg, const int* __restrict__ Mg,
               float* __restrict__ Og, const _Float16* __restrict__ Kh,
               const _Float16* __restrict__ Vt) {
  __shared__ __align__(16) _Float16 sK[64][136];    // padded linear, 17.4 KB
  __shared__ __align__(16) _Float16 sV[128][72];    // padded linear, 18.4 KB
  __shared__ __align__(16) _Float16 sPw[8][16][72]; // per-wave P bounce, 18.4 KB
  __shared__ float sRinv[QBR];

  const int bid0 = blockIdx.x;
  const int bid  = (bid0 & 7) * (NBLK >> 3) + (bid0 >> 3);   // XCD swizzle (1024%8==0)
  const int bh = bid >> 4;
  const int qt = bid & (NQT - 1);

  const int tid  = threadIdx.x;
  const int lane = tid & 63;
  const int w = tid >> 6;          // wave 0..7 owns q-rows w*16..w*16+15
  const int g = lane >> 4;
  const int c = lane & 15;

  // Q A-frags: lane holds Q[qrow = w*16 + c][d = ch*32 + g*8 + j]  (R2-R5 layout)
  f16x8 aq[4];
  {
    const float* qp = Qg + ((long)bh * Sc + (long)qt * QBR + w * 16 + c) * Dc + g * 8;
    #pragma unroll
    for (int ch = 0; ch < 4; ch++) aq[ch] = loadcvt8h(qp + ch * 32);
  }

  const _Float16* Kplane = Kh + (long)bh * Sc * Dc;
  const _Float16* Vplane = Vt + (long)bh * Dc * Sc;
  const int* Mwave = Mg + ((long)bh * Sc + (long)qt * QBR + w * 16 + g * 4) * Sc;

  // staging geometry: 1024 16B-units each for K and V; thread covers unit tid, tid+512
  const int kr0 = tid >> 4, kd0 = tid & 15;    // K: row 0..31 (+32), dcol8 0..15
  const int vr0 = tid >> 3, vc0 = tid & 7;     // V: drow 0..63 (+64), kcol8 0..7

  auto loadK = [&](int cc, f16x8& a, f16x8& b) {
    a = *(const f16x8*)(Kplane + (long)(cc * 64 + kr0) * Dc + kd0 * 8);
    b = *(const f16x8*)(Kplane + (long)(cc * 64 + kr0 + 32) * Dc + kd0 * 8);
  };
  auto stageK = [&](const f16x8& a, const f16x8& b) {
    *(f16x8*)&sK[kr0][kd0 * 8] = a;
    *(f16x8*)&sK[kr0 + 32][kd0 * 8] = b;
  };
  auto loadV = [&](int cc, f16x8& a, f16x8& b) {
    a = *(const f16x8*)(Vplane + (long)vr0 * Sc + cc * 64 + vc0 * 8);
    b = *(const f16x8*)(Vplane + (long)(vr0 + 64) * Sc + cc * 64 + vc0 * 8);
  };
  auto stageV = [&](const f16x8& a, const f16x8& b) {
    *(f16x8*)&sV[vr0][vc0 * 8] = a;
    *(f16x8*)&sV[vr0 + 64][vc0 * 8] = b;
  };

  // QK^T 16x16 tile nt from sK (linear reads; 2-way bank alias = free)
  auto qkTile = [&](int nt) -> f32x4 {
    const _Float16* kb = &sK[nt * 16 + c][g * 8];
    f16x8 b0 = *(const f16x8*)kb;
    f16x8 b1 = *(const f16x8*)(kb + 32);
    f16x8 b2 = *(const f16x8*)(kb + 64);
    f16x8 b3 = *(const f16x8*)(kb + 96);
    f32x4 s = {0.f, 0.f, 0.f, 0.f};
    s = __builtin_amdgcn_mfma_f32_16x16x32_f16(aq[0], b0, s, 0, 0, 0);
    s = __builtin_amdgcn_mfma_f32_16x16x32_f16(aq[1], b1, s, 0, 0, 0);
    s = __builtin_amdgcn_mfma_f32_16x16x32_f16(aq[2], b2, s, 0, 0, 0);
    s = __builtin_amdgcn_mfma_f32_16x16x32_f16(aq[3], b3, s, 0, 0, 0);
    return s;
  };

  // ---- pass A: rowsums of exp(masked QK^T / sqrt(dk))
  float rs[4] = {0.f, 0.f, 0.f, 0.f};
  {
    f16x8 ka, kb2;
    loadK(0, ka, kb2);
    for (int cc = 0; cc < 32; cc++) {
      __syncthreads();                 // prior chunk's readers done
      stageK(ka, kb2);
      __syncthreads();                 // sK ready
      if (cc + 1 < 32) loadK(cc + 1, ka, kb2);  // prefetch: hides under compute below
      int mv[4][4];
      const int* mp = Mwave + cc * 64 + c;
      #pragma unroll
      for (int nt = 0; nt < 4; nt++)
        #pragma unroll
        for (int r = 0; r < 4; r++)
          mv[nt][r] = mp[(long)r * Sc + nt * 16];
      #pragma unroll
      for (int nt = 0; nt < 4; nt++) {
        f32x4 s = qkTile(nt);
        #pragma unroll
        for (int r = 0; r < 4; r++) {
          float e = (mv[nt][r] != 0) ? __expf(s[r] * SCALEF) : 0.f;
          rs[r] += (float)(_Float16)e;   // fp16-rounded, matches pass B exactly
        }
      }
    }
  }
  #pragma unroll
  for (int r = 0; r < 4; r++) {
    float x = rs[r];
    x += __shfl_xor(x, 1);
    x += __shfl_xor(x, 2);
    x += __shfl_xor(x, 4);
    x += __shfl_xor(x, 8);
    if (c == 0) sRinv[w * 16 + g * 4 + r] = (x > 0.f) ? (1.f / x) : 0.f;
  }
  __syncthreads();                     // sRinv visible (de-risked handoff)
  const float rinvW = sRinv[w * 16 + (lane >> 2)];
  float rinvO[4];
  #pragma unroll
  for (int r = 0; r < 4; r++) rinvO[r] = sRinv[w * 16 + g * 4 + r];

  // ---- pass B: recompute S -> P bounce -> weights write + PV accumulate
  f32x4 oacc[8];
  #pragma unroll
  for (int dt = 0; dt < 8; dt++) oacc[dt] = (f32x4){0.f, 0.f, 0.f, 0.f};
  float* wbase = Og + OUTE + ((long)bh * Sc + (long)qt * QBR + w * 16) * Sc;
  const int wr = lane >> 2;        // weights row within wave tile
  const int wq = lane & 3;         // weights col quarter (16 cols)

  {
    f16x8 ka, kb2, va, vb2;
    loadK(0, ka, kb2);
    loadV(0, va, vb2);
    for (int cc = 0; cc < 32; cc++) {
      __syncthreads();
      stageK(ka, kb2);
      stageV(va, vb2);
      __syncthreads();
      if (cc + 1 < 32) {
        loadK(cc + 1, ka, kb2);
        loadV(cc + 1, va, vb2);
      }
      int mv[4][4];
      const int* mp = Mwave + cc * 64 + c;
      #pragma unroll
      for (int nt = 0; nt < 4; nt++)
        #pragma unroll
        for (int r = 0; r < 4; r++)
          mv[nt][r] = mp[(long)r * Sc + nt * 16];
      // QK^T + exp -> bounce (identical compute to pass A)
      #pragma unroll
      for (int nt = 0; nt < 4; nt++) {
        f32x4 s = qkTile(nt);
        #pragma unroll
        for (int r = 0; r < 4; r++) {
          float e = (mv[nt][r] != 0) ? __expf(s[r] * SCALEF) : 0.f;
          sPw[w][g * 4 + r][nt * 16 + c] = (_Float16)e;
        }
      }
      // weights: row wr, cols wq*16..+15 (wave-local LDS dep; lgkmcnt ordered)
      {
        f16x8 p0 = *(const f16x8*)&sPw[w][wr][wq * 16];
        f16x8 p1 = *(const f16x8*)&sPw[w][wr][wq * 16 + 8];
        float* dst = wbase + (long)wr * Sc + cc * 64 + wq * 16;
        float4 o0, o1, o2, o3;
        o0.x = (float)p0[0] * rinvW; o0.y = (float)p0[1] * rinvW;
        o0.z = (float)p0[2] * rinvW; o0.w = (float)p0[3] * rinvW;
        o1.x = (float)p0[4] * rinvW; o1.y = (float)p0[5] * rinvW;
        o1.z = (float)p0[6] * rinvW; o1.w = (float)p0[7] * rinvW;
        o2.x = (float)p1[0] * rinvW; o2.y = (float)p1[1] * rinvW;
        o2.z = (float)p1[2] * rinvW; o2.w = (float)p1[3] * rinvW;
        o3.x = (float)p1[4] * rinvW; o3.y = (float)p1[5] * rinvW;
        o3.z = (float)p1[6] * rinvW; o3.w = (float)p1[7] * rinvW;
        *(float4*)dst = o0;
        *(float4*)(dst + 4) = o1;
        *(float4*)(dst + 8) = o2;
        *(float4*)(dst + 12) = o3;
      }
      // PV: A-frags from bounce, B-frags from sV (linear)
      f16x8 pa0 = *(const f16x8*)&sPw[w][c][g * 8];
      f16x8 pa1 = *(const f16x8*)&sPw[w][c][32 + g * 8];
      #pragma unroll
      for (int dt = 0; dt < 8; dt++) {
        const _Float16* vb = &sV[dt * 16 + c][g * 8];
        f16x8 v0 = *(const f16x8*)vb;
        f16x8 v1 = *(const f16x8*)(vb + 32);
        oacc[dt] = __builtin_amdgcn_mfma_f32_16x16x32_f16(pa0, v0, oacc[dt], 0, 0, 0);
        oacc[dt] = __builtin_amdgcn_mfma_f32_16x16x32_f16(pa1, v1, oacc[dt], 0, 0, 0);
      }
    }
  }

  // ---- epilogue: out = oacc * rinv
  float* ob = Og + ((long)bh * Sc + (long)qt * QBR + w * 16 + g * 4) * Dc;
  #pragma unroll
  for (int r = 0; r < 4; r++) {
    #pragma unroll
    for (int dt = 0; dt < 8; dt++) {
      ob[(long)r * Dc + dt * 16 + c] = oacc[dt][r] * rinvO[r];
    }
  }
}

// ---- fallback (ws too small): simple, correct, slow. One wave per q-row.
__global__ __launch_bounds__(256)
void sdpa_naive(const float* __restrict__ Qg, const float* __restrict__ Kg,
                const float* __restrict__ Vg, const int* __restrict__ Mg,
                float* __restrict__ Og) {
  __shared__ float sE[4][Sc];
  const int bh = blockIdx.x >> 9;
  const int rg = blockIdx.x & 511;
  const int wv = threadIdx.x >> 6, ln = threadIdx.x & 63;
  const int qrow = rg * 4 + wv;
  const float* qp = Qg + ((long)bh * Sc + qrow) * Dc;
  const int* mp = Mg + ((long)bh * Sc + qrow) * Sc;
  float rsum = 0.f;
  for (int k0 = 0; k0 < Sc; k0 += 64) {
    const int kcol = k0 + ln;
    const float* kp = Kg + ((long)bh * Sc + kcol) * Dc;
    float s = 0.f;
    for (int d = 0; d < Dc; d++) s += qp[d] * kp[d];
    float e = (mp[kcol] != 0) ? __expf(s * SCALEF) : 0.f;
    e = (float)(_Float16)e;
    sE[wv][kcol] = e;
    rsum += e;
  }
  for (int o = 1; o < 64; o <<= 1) rsum += __shfl_xor(rsum, o);
  float oa = 0.f, ob2 = 0.f;
  for (int k = 0; k < Sc; k++) {
    const float e = sE[wv][k];
    const float* vp = Vg + ((long)bh * Sc + k) * Dc;
    oa += e * vp[ln];
    ob2 += e * vp[ln + 64];
  }
  const float ri = (rsum > 0.f) ? 1.f / rsum : 0.f;
  float* op = Og + ((long)bh * Sc + qrow) * Dc;
  op[ln] = oa * ri;
  op[ln + 64] = ob2 * ri;
  float* wb = Og + OUTE + ((long)bh * Sc + qrow) * Sc;
  for (int k = ln; k < Sc; k += 64) wb[k] = sE[wv][k] * ri;
}

extern "C" void kernel_launch(void* const* d_in, const int* in_sizes, int n_in,
                              void* d_out, int out_size, void* d_ws, size_t ws_size,
                              hipStream_t stream) {
  (void)in_sizes; (void)n_in; (void)out_size;
  const float* q = (const float*)d_in[0];
  const float* k = (const float*)d_in[1];
  const float* v = (const float*)d_in[2];
  const int* m = (const int*)d_in[3];
  float* out = (float*)d_out;

  const size_t need = 2UL * KVE * sizeof(_Float16);  // Kh + Vt = 67 MB
  if (d_ws != nullptr && ws_size >= need) {
    _Float16* Kh = (_Float16*)d_ws;
    _Float16* Vt = Kh + KVE;
    hipLaunchKernelGGL(kconv_kernel, dim3((int)(KVE / 8 / 256)), dim3(256), 0, stream, k, Kh);
    hipLaunchKernelGGL(vtrans_kernel, dim3(BHc * 32), dim3(256), 0, stream, v, Vt);
    hipLaunchKernelGGL(sdpa_main, dim3(NBLK), dim3(512), 0, stream, q, m, out, Kh, Vt);
  } else {
    hipLaunchKernelGGL(sdpa_naive, dim3(BHc * 512), dim3(256), 0, stream, q, k, v, m, out);
  }
}